// Round 1
// baseline (523.203 us; speedup 1.0000x reference)
//
#include <hip/hip_runtime.h>

// Problem constants: S=32, FRAME=8, CLS=32, D=512, HWA=8x8=64, HWV=14x14=196, DOUT=128

typedef __attribute__((ext_vector_type(8))) short bf16x8;
typedef __attribute__((ext_vector_type(4))) float f32x4;

__device__ __forceinline__ unsigned short f2bf(float x) {
    union { float f; unsigned u; } v; v.f = x;
    unsigned r = v.u + 0x7FFFu + ((v.u >> 16) & 1u);
    return (unsigned short)(r >> 16);
}
__device__ __forceinline__ unsigned pk2(float a, float b) {
    return (unsigned)f2bf(a) | ((unsigned)f2bf(b) << 16);
}

// ---------------- Kernel 1: fa[b][o] = max_hw( sum_i Wt[o][i]*feat_a[b][i][hw] ) + bt[o]
// grid (4 otile, 1024 b), block 256 (4 waves). MFMA 16x16x32 bf16.
// A = Wt (M=o 128-tile, K=i), B = feat_a[b] (K=i, N=hw 64). Staged via LDS with fp32->bf16 cvt.
__global__ __launch_bounds__(256) void k1_fa(
    const float* __restrict__ feat_a, const float* __restrict__ Wt,
    const float* __restrict__ bt, float* __restrict__ fa)
{
    __shared__ unsigned short lds_a[128][40]; // [o][k], pad 32->40 (bank stride 20 mod 32)
    __shared__ unsigned short lds_b[64][40];  // [hw][k] transposed
    const int ot = blockIdx.x, b = blockIdx.y, t = threadIdx.x;
    const int w = t >> 6, l = t & 63, lo = l & 15, hi = l >> 4;

    f32x4 acc[2][4];
#pragma unroll
    for (int i = 0; i < 2; ++i)
#pragma unroll
        for (int j = 0; j < 4; ++j) acc[i][j] = (f32x4)(0.f);

    const int r_a = t >> 1, h_a = t & 1;      // A staging: row, k-half
    const int kk = t & 31, hw0 = (t >> 5) * 8; // B staging: k, hw-start

    for (int k0 = 0; k0 < 512; k0 += 32) {
        { // stage A tile: Wt[ot*128 + r_a][k0 + h_a*16 .. +16)
            const float4* src = (const float4*)&Wt[(ot*128 + r_a)*512 + k0 + h_a*16];
            float4 f0 = src[0], f1 = src[1], f2 = src[2], f3 = src[3];
            uint4 u0 = { pk2(f0.x,f0.y), pk2(f0.z,f0.w), pk2(f1.x,f1.y), pk2(f1.z,f1.w) };
            uint4 u1 = { pk2(f2.x,f2.y), pk2(f2.z,f2.w), pk2(f3.x,f3.y), pk2(f3.z,f3.w) };
            *(uint4*)&lds_a[r_a][h_a*16]     = u0;
            *(uint4*)&lds_a[r_a][h_a*16 + 8] = u1;
        }
        { // stage B tile transposed: feat_a[b][k0+kk][hw0..hw0+8) -> lds_b[hw][kk]
            const float4* src = (const float4*)&feat_a[(b*512 + k0 + kk)*64 + hw0];
            float4 f0 = src[0], f1 = src[1];
            lds_b[hw0+0][kk] = f2bf(f0.x);
            lds_b[hw0+1][kk] = f2bf(f0.y);
            lds_b[hw0+2][kk] = f2bf(f0.z);
            lds_b[hw0+3][kk] = f2bf(f0.w);
            lds_b[hw0+4][kk] = f2bf(f1.x);
            lds_b[hw0+5][kk] = f2bf(f1.y);
            lds_b[hw0+6][kk] = f2bf(f1.z);
            lds_b[hw0+7][kk] = f2bf(f1.w);
        }
        __syncthreads();
        bf16x8 av[2], bv4[4];
#pragma unroll
        for (int mo = 0; mo < 2; ++mo)
            av[mo] = *(const bf16x8*)&lds_a[w*32 + mo*16 + lo][hi*8];
#pragma unroll
        for (int nf = 0; nf < 4; ++nf)
            bv4[nf] = *(const bf16x8*)&lds_b[nf*16 + lo][hi*8];
#pragma unroll
        for (int mo = 0; mo < 2; ++mo)
#pragma unroll
            for (int nf = 0; nf < 4; ++nf)
                acc[mo][nf] = __builtin_amdgcn_mfma_f32_16x16x32_bf16(av[mo], bv4[nf], acc[mo][nf], 0, 0, 0);
        __syncthreads();
    }
    // epilogue: D row=(l>>4)*4+reg (o), col=l&15 (hw). max over hw = max over nf then lanes lo=0..15.
#pragma unroll
    for (int mo = 0; mo < 2; ++mo)
#pragma unroll
        for (int reg = 0; reg < 4; ++reg) {
            float m = fmaxf(fmaxf(acc[mo][0][reg], acc[mo][1][reg]),
                            fmaxf(acc[mo][2][reg], acc[mo][3][reg]));
            m = fmaxf(m, __shfl_xor(m, 1));
            m = fmaxf(m, __shfl_xor(m, 2));
            m = fmaxf(m, __shfl_xor(m, 4));
            m = fmaxf(m, __shfl_xor(m, 8));
            if (lo == 0) {
                int orow = ot*128 + w*32 + mo*16 + hi*4 + reg;
                fa[b*512 + orow] = m + bt[orow];
            }
        }
}

// ---------------- Kernel 2: g[b][c][i] = sum_hw feat_v[b][i][hw]*cam[b][c][hw]; camsum[b][c]
// grid 256 (b), block 256 (4 waves). MFMA: A=cam (M=c 32, K=hw 196 pad 224), B=feat_v^T (N=i).
__global__ __launch_bounds__(256) void k2_g(
    const float* __restrict__ feat_v, const float* __restrict__ cam,
    unsigned short* __restrict__ g_bf, float* __restrict__ camsum)
{
    __shared__ unsigned short cam_s[32][232];  // [c][hw pad]
    __shared__ unsigned short feat_s[64][232]; // [i-chunk][hw pad]
    const int b = blockIdx.x, t = threadIdx.x;
    const int w = t >> 6, l = t & 63, lo = l & 15, hi = l >> 4;

    const float* camb = &cam[b * 32 * 196];
    for (int i4 = t; i4 < 1568; i4 += 256) { // 32*196/4; rows are 49 float4s exactly
        int c = i4 / 49, h4 = (i4 - c*49) * 4;
        float4 v = ((const float4*)camb)[i4];
        *(unsigned*)&cam_s[c][h4]     = pk2(v.x, v.y);
        *(unsigned*)&cam_s[c][h4 + 2] = pk2(v.z, v.w);
    }
    for (int idx = t; idx < 32*28; idx += 256) { // zero-fill k=196..223
        int c = idx / 28, hh = 196 + (idx - c*28);
        cam_s[c][hh] = 0;
    }
    if (t < 32) { // camsum in fp32 from global
        float s = 0.f;
        const float* p = &camb[t * 196];
        for (int q = 0; q < 196; ++q) s += p[q];
        camsum[b*32 + t] = s;
    }

    for (int ic = 0; ic < 8; ++ic) { // i-chunks of 64
        __syncthreads();
        const float* fb = &feat_v[(b*512 + ic*64) * 196];
        for (int i4 = t; i4 < 3136; i4 += 256) { // 64*196/4
            int r = i4 / 49, h4 = (i4 - r*49) * 4;
            float4 v = ((const float4*)fb)[i4];
            *(unsigned*)&feat_s[r][h4]     = pk2(v.x, v.y);
            *(unsigned*)&feat_s[r][h4 + 2] = pk2(v.z, v.w);
        }
        for (int idx = t; idx < 64*28; idx += 256) {
            int r = idx / 28, hh = 196 + (idx - r*28);
            feat_s[r][hh] = 0;
        }
        __syncthreads();
        f32x4 acc[2]; acc[0] = (f32x4)(0.f); acc[1] = (f32x4)(0.f);
#pragma unroll
        for (int kt = 0; kt < 7; ++kt) {
            bf16x8 a0 = *(const bf16x8*)&cam_s[lo][kt*32 + hi*8];
            bf16x8 a1 = *(const bf16x8*)&cam_s[16 + lo][kt*32 + hi*8];
            bf16x8 bb = *(const bf16x8*)&feat_s[w*16 + lo][kt*32 + hi*8];
            acc[0] = __builtin_amdgcn_mfma_f32_16x16x32_bf16(a0, bb, acc[0], 0, 0, 0);
            acc[1] = __builtin_amdgcn_mfma_f32_16x16x32_bf16(a1, bb, acc[1], 0, 0, 0);
        }
#pragma unroll
        for (int mo = 0; mo < 2; ++mo)
#pragma unroll
            for (int reg = 0; reg < 4; ++reg) {
                int c = mo*16 + hi*4 + reg;
                int i = ic*64 + w*16 + lo;
                g_bf[(b*32 + c)*512 + i] = f2bf(acc[mo][reg]);
            }
    }
}

// ---------------- Kernel 3: Wvs[o][i] = sum_d Wv[o][d]*Ws[d][i] (bf16 out); wvbs[o] = Wv[o]·bs
__global__ __launch_bounds__(256) void k3_wvs(
    const float* __restrict__ Wv, const float* __restrict__ Ws, const float* __restrict__ bs,
    unsigned short* __restrict__ Wvs_bf, float* __restrict__ wvbs)
{
    __shared__ float red[256];
    const int o = blockIdx.x, t = threadIdx.x;
    float a0 = 0.f, a1 = 0.f;
    for (int d = 0; d < 512; ++d) {
        float wv = Wv[o*512 + d];
        a0 += wv * Ws[d*512 + t];
        a1 += wv * Ws[d*512 + t + 256];
    }
    Wvs_bf[o*512 + t]       = f2bf(a0);
    Wvs_bf[o*512 + t + 256] = f2bf(a1);
    red[t] = Wv[o*512 + t] * bs[t] + Wv[o*512 + t + 256] * bs[t + 256];
    __syncthreads();
    for (int s2 = 128; s2 > 0; s2 >>= 1) {
        if (t < s2) red[t] += red[t + s2];
        __syncthreads();
    }
    if (t == 0) wvbs[o] = red[0];
}

// ---------------- Kernel 4: tv[bc][o] = (g[bc]·Wvs[o] + cs*wvbs[o])/(cs+1e-10) + bv[o]
// grid 256 (M-tiles of 32), block 64 (1 wave). Fragments direct from global (L2-resident).
__global__ __launch_bounds__(64) void k4_tv(
    const unsigned short* __restrict__ g_bf, const unsigned short* __restrict__ Wvs_bf,
    const float* __restrict__ camsum, const float* __restrict__ wvbs,
    const float* __restrict__ bv, float* __restrict__ tv)
{
    const int m0 = blockIdx.x * 32;
    const int l = threadIdx.x, lo = l & 15, hi = l >> 4;
    f32x4 acc[2][8];
#pragma unroll
    for (int i = 0; i < 2; ++i)
#pragma unroll
        for (int j = 0; j < 8; ++j) acc[i][j] = (f32x4)(0.f);
    for (int k0 = 0; k0 < 512; k0 += 32) {
        bf16x8 a0 = *(const bf16x8*)&g_bf[(m0 + lo)*512 + k0 + hi*8];
        bf16x8 a1 = *(const bf16x8*)&g_bf[(m0 + 16 + lo)*512 + k0 + hi*8];
#pragma unroll
        for (int nf = 0; nf < 8; ++nf) {
            bf16x8 bb = *(const bf16x8*)&Wvs_bf[(nf*16 + lo)*512 + k0 + hi*8];
            acc[0][nf] = __builtin_amdgcn_mfma_f32_16x16x32_bf16(a0, bb, acc[0][nf], 0, 0, 0);
            acc[1][nf] = __builtin_amdgcn_mfma_f32_16x16x32_bf16(a1, bb, acc[1][nf], 0, 0, 0);
        }
    }
#pragma unroll
    for (int mo = 0; mo < 2; ++mo)
#pragma unroll
        for (int reg = 0; reg < 4; ++reg) {
            int bc = m0 + mo*16 + hi*4 + reg;
            float cs = camsum[bc];
            float inv = 1.f / (cs + 1e-10f);
#pragma unroll
            for (int nf = 0; nf < 8; ++nf) {
                int o = nf*16 + lo;
                tv[bc*128 + o] = (acc[mo][nf][reg] + cs * wvbs[o]) * inv + bv[o];
            }
        }
}

// ---------------- Kernel 5: ta[row][o] = fa[row]·Wa[o] + ba[o]   (fp32 for accuracy)
// grid 128 (8 rows each), block 128 (o)
__global__ __launch_bounds__(128) void k5_ta(
    const float* __restrict__ fa, const float* __restrict__ Wa,
    const float* __restrict__ ba, float* __restrict__ ta)
{
    __shared__ float fa_s[8 * 512];
    const int r0 = blockIdx.x * 8, t = threadIdx.x;
    for (int j = t; j < 1024; j += 128)
        ((float4*)fa_s)[j] = ((const float4*)&fa[r0 * 512])[j];
    __syncthreads();
    float acc[8];
#pragma unroll
    for (int r = 0; r < 8; ++r) acc[r] = 0.f;
    const float4* wa4 = (const float4*)&Wa[t * 512];
    for (int j = 0; j < 128; ++j) {
        float4 wv = wa4[j];
#pragma unroll
        for (int r = 0; r < 8; ++r) {
            float4 fv = ((const float4*)&fa_s[r * 512])[j];
            acc[r] += wv.x*fv.x + wv.y*fv.y + wv.z*fv.z + wv.w*fv.w;
        }
    }
    float bao = ba[t];
#pragma unroll
    for (int r = 0; r < 8; ++r) ta[(r0 + r)*128 + t] = acc[r] + bao;
}

// ---------------- Kernel 6: losses. grid 1024 (s*32+c), block 64.
__global__ __launch_bounds__(64) void k6_loss(
    const float* __restrict__ ta, const float* __restrict__ tv,
    const float* __restrict__ pred_a, const float* __restrict__ pred_v,
    const int* __restrict__ rand_frames, const int* __restrict__ rand_classes,
    float* __restrict__ out)
{
    const int blk = blockIdx.x;
    const int s = blk >> 5, c = blk & 31;
    const int t = threadIdx.x;
    const float ta0 = ta[blk*128 + t], ta1 = ta[blk*128 + 64 + t];
    const float pa = pred_a[blk];
    const bool aa = pa > 0.3f;
    const int num = (int)(pa * 8.0f);
    for (int f = 0; f < 8; ++f) {
        // co: tv row (s,f,c)
        int row = (s*8 + f)*32 + c;
        float d0 = ta0 - tv[row*128 + t];
        float d1 = ta1 - tv[row*128 + 64 + t];
        float ss = d0*d0 + d1*d1;
        for (int m = 32; m > 0; m >>= 1) ss += __shfl_xor(ss, m);
        float pv = pred_v[(s*8 + f)*32 + c];
        bool av = (1.f / (1.f + expf(-pv))) > 0.3f;
        if (t == 0) out[blk*8 + f] = (aa && av) ? ss * (1.f/128.f) : 0.f;
        // di: tv row (s^1, rand_frames, rand_classes)
        int fi = rand_frames[blk*8 + f];
        int ci = rand_classes[blk*8 + f];
        int row2 = ((s ^ 1)*8 + fi)*32 + ci;
        float e0 = ta0 - tv[row2*128 + t];
        float e1 = ta1 - tv[row2*128 + 64 + t];
        float s2 = e0*e0 + e1*e1;
        for (int m = 32; m > 0; m >>= 1) s2 += __shfl_xor(s2, m);
        if (t == 0) out[8192 + blk*8 + f] = (aa && (f < num)) ? s2 * (1.f/128.f) : 0.f;
    }
}

extern "C" void kernel_launch(void* const* d_in, const int* in_sizes, int n_in,
                              void* d_out, int out_size, void* d_ws, size_t ws_size,
                              hipStream_t stream) {
    const float* feat_a = (const float*)d_in[0];
    const float* pred_a = (const float*)d_in[1];
    const float* feat_v = (const float*)d_in[2];
    const float* pred_v = (const float*)d_in[3];
    const float* cam    = (const float*)d_in[4];
    const int* rand_frames  = (const int*)d_in[5];
    const int* rand_classes = (const int*)d_in[6];
    const float* Wt = (const float*)d_in[7];
    const float* bt = (const float*)d_in[8];
    const float* Ws = (const float*)d_in[9];
    const float* bs = (const float*)d_in[10];
    const float* Wa = (const float*)d_in[11];
    const float* ba = (const float*)d_in[12];
    const float* Wv = (const float*)d_in[13];
    const float* bv = (const float*)d_in[14];
    float* out = (float*)d_out;

    char* ws = (char*)d_ws;
    float* fa              = (float*)(ws + 0);                 // 1024*512*4   = 2 MB
    float* ta              = (float*)(ws + 2097152);           // 1024*128*4   = 512 KB
    unsigned short* g_bf   = (unsigned short*)(ws + 2621440);  // 8192*512*2   = 8 MB
    float* camsum          = (float*)(ws + 11010048);          // 8192*4       = 32 KB
    unsigned short* Wvs_bf = (unsigned short*)(ws + 11042816); // 128*512*2    = 128 KB
    float* wvbs            = (float*)(ws + 11173888);          // 128*4
    float* tv              = (float*)(ws + 11174400);          // 8192*128*4   = 4 MB

    k3_wvs<<<128, 256, 0, stream>>>(Wv, Ws, bs, Wvs_bf, wvbs);
    k1_fa<<<dim3(4, 1024), 256, 0, stream>>>(feat_a, Wt, bt, fa);
    k2_g<<<256, 256, 0, stream>>>(feat_v, cam, g_bf, camsum);
    k4_tv<<<256, 64, 0, stream>>>(g_bf, Wvs_bf, camsum, wvbs, bv, tv);
    k5_ta<<<128, 128, 0, stream>>>(fa, Wa, ba, ta);
    k6_loss<<<1024, 64, 0, stream>>>(ta, tv, pred_a, pred_v, rand_frames, rand_classes, out);
}

// Round 2
// 460.895 us; speedup vs baseline: 1.1352x; 1.1352x over previous
//
#include <hip/hip_runtime.h>

// Problem constants: S=32, FRAME=8, CLS=32, D=512, HWA=8x8=64, HWV=14x14=196, DOUT=128

typedef __attribute__((ext_vector_type(8))) short bf16x8;
typedef __attribute__((ext_vector_type(4))) float f32x4;

__device__ __forceinline__ unsigned short f2bf(float x) {
    union { float f; unsigned u; } v; v.f = x;
    unsigned r = v.u + 0x7FFFu + ((v.u >> 16) & 1u);
    return (unsigned short)(r >> 16);
}
__device__ __forceinline__ unsigned pk2(float a, float b) {
    return (unsigned)f2bf(a) | ((unsigned)f2bf(b) << 16);
}

// ---------------- Kernel 0: Wt -> bf16 [o][i] (once; L2-resident for k1)
__global__ __launch_bounds__(256) void k0_wtbf(
    const float* __restrict__ Wt, unsigned short* __restrict__ Wt_bf)
{
    int i = blockIdx.x * 256 + threadIdx.x; // 512*512/4 = 65536 float4
    float4 v = ((const float4*)Wt)[i];
    *(unsigned*)&Wt_bf[i*4]     = pk2(v.x, v.y);
    *(unsigned*)&Wt_bf[i*4 + 2] = pk2(v.z, v.w);
}

// ---------------- Kernel 1: fa[b][o] = max_hw( sum_i Wt[o][i]*feat_a[b][i][hw] ) + bt[o]
// One block per b (256 thr, 4 waves). feat_a[b] staged ONCE to LDS [hw][k] bf16
// (64KB, chunk-XOR swizzle). Wave w computes o in [w*128, w*128+128): 8x4 frags.
// A-fragments read directly from global Wt_bf (L2-resident). No k-loop barriers.
__global__ __launch_bounds__(256, 2) void k1_fa(
    const float* __restrict__ feat_a, const unsigned short* __restrict__ Wt_bf,
    const float* __restrict__ bt, float* __restrict__ fa)
{
    __shared__ unsigned short lds_b[64 * 512]; // [hw][k], 65536 B, swizzled chunks
    const int b = blockIdx.x, t = threadIdx.x;
    const int w = t >> 6, l = t & 63, lo = l & 15, hi = l >> 4;

    // ---- stage: lane = hw (l), wave w handles koct = it*4 + w
    const float* fb = feat_a + (size_t)b * 512 * 64;
    const int hw = l;
#pragma unroll 2
    for (int it = 0; it < 16; ++it) {
        int koct = it * 4 + w; // 0..63
        float v[8];
#pragma unroll
        for (int j = 0; j < 8; ++j)
            v[j] = fb[(koct * 8 + j) * 64 + hw]; // wave-wide coalesced 256B row read
        unsigned u[4];
#pragma unroll
        for (int j = 0; j < 4; ++j) u[j] = pk2(v[2*j], v[2*j + 1]);
        int chunk = koct ^ (hw & 7); // XOR swizzle (16B chunk index within row)
        *(uint4*)((char*)lds_b + hw * 1024 + chunk * 16) = *(uint4*)u;
    }
    __syncthreads();

    // ---- compute
    f32x4 acc[8][4];
#pragma unroll
    for (int i = 0; i < 8; ++i)
#pragma unroll
        for (int j = 0; j < 4; ++j) acc[i][j] = (f32x4)(0.f);
    const int o0 = w * 128;
    for (int ks = 0; ks < 16; ++ks) {
        bf16x8 bfr[4];
#pragma unroll
        for (int nf = 0; nf < 4; ++nf) {
            int ko = ks * 4 + hi;
            int chunk = ko ^ (lo & 7); // row = nf*16+lo -> row&7 == lo&7
            bfr[nf] = *(const bf16x8*)((char*)lds_b + (nf*16 + lo) * 1024 + chunk * 16);
        }
#pragma unroll
        for (int mo = 0; mo < 8; ++mo) {
            bf16x8 afr = *(const bf16x8*)&Wt_bf[(o0 + mo*16 + lo) * 512 + ks*32 + hi*8];
#pragma unroll
            for (int nf = 0; nf < 4; ++nf)
                acc[mo][nf] = __builtin_amdgcn_mfma_f32_16x16x32_bf16(afr, bfr[nf], acc[mo][nf], 0, 0, 0);
        }
    }
    // ---- epilogue: D row=(l>>4)*4+reg (o), col=l&15 (hw). max over nf then 16 lanes.
#pragma unroll
    for (int mo = 0; mo < 8; ++mo)
#pragma unroll
        for (int reg = 0; reg < 4; ++reg) {
            float m = fmaxf(fmaxf(acc[mo][0][reg], acc[mo][1][reg]),
                            fmaxf(acc[mo][2][reg], acc[mo][3][reg]));
            m = fmaxf(m, __shfl_xor(m, 1));
            m = fmaxf(m, __shfl_xor(m, 2));
            m = fmaxf(m, __shfl_xor(m, 4));
            m = fmaxf(m, __shfl_xor(m, 8));
            if (lo == 0) {
                int orow = o0 + mo*16 + hi*4 + reg;
                fa[(size_t)b * 512 + orow] = m + bt[orow];
            }
        }
}

// ---------------- Kernel 2: g[b][c][i] = sum_hw feat_v[b][i][hw]*cam[b][c][hw]; camsum[b][c]
// grid (2 half, 256 b), block 256. Each block: 4 i-chunks of 64 (half*256..+256).
__global__ __launch_bounds__(256) void k2_g(
    const float* __restrict__ feat_v, const float* __restrict__ cam,
    unsigned short* __restrict__ g_bf, float* __restrict__ camsum)
{
    __shared__ unsigned short cam_s[32][232];  // [c][hw pad]
    __shared__ unsigned short feat_s[64][232]; // [i-chunk][hw pad]
    const int half = blockIdx.x, b = blockIdx.y, t = threadIdx.x;
    const int w = t >> 6, l = t & 63, lo = l & 15, hi = l >> 4;

    const float* camb = &cam[b * 32 * 196];
    for (int i4 = t; i4 < 1568; i4 += 256) { // 32*196/4
        int c = i4 / 49, h4 = (i4 - c*49) * 4;
        float4 v = ((const float4*)camb)[i4];
        *(unsigned*)&cam_s[c][h4]     = pk2(v.x, v.y);
        *(unsigned*)&cam_s[c][h4 + 2] = pk2(v.z, v.w);
    }
    for (int idx = t; idx < 32*28; idx += 256) { // zero-fill k=196..223
        int c = idx / 28, hh = 196 + (idx - c*28);
        cam_s[c][hh] = 0;
    }
    if (half == 0) { // camsum fp32, parallel: 8 segs per c, shfl-reduce
        int c = t >> 3, seg = t & 7;
        int h0 = seg * 25, h1 = min(196, h0 + 25);
        float s = 0.f;
        const float* p = &camb[c * 196];
        for (int q = h0; q < h1; ++q) s += p[q];
        s += __shfl_xor(s, 1);
        s += __shfl_xor(s, 2);
        s += __shfl_xor(s, 4);
        if (seg == 0) camsum[b*32 + c] = s;
    }

    for (int ic = half*4; ic < half*4 + 4; ++ic) { // i-chunks of 64
        __syncthreads();
        const float* fbv = &feat_v[((size_t)b*512 + ic*64) * 196];
        for (int i4 = t; i4 < 3136; i4 += 256) { // 64*196/4
            int r = i4 / 49, h4 = (i4 - r*49) * 4;
            float4 v = ((const float4*)fbv)[i4];
            *(unsigned*)&feat_s[r][h4]     = pk2(v.x, v.y);
            *(unsigned*)&feat_s[r][h4 + 2] = pk2(v.z, v.w);
        }
        for (int idx = t; idx < 64*28; idx += 256) {
            int r = idx / 28, hh = 196 + (idx - r*28);
            feat_s[r][hh] = 0;
        }
        __syncthreads();
        f32x4 acc[2]; acc[0] = (f32x4)(0.f); acc[1] = (f32x4)(0.f);
#pragma unroll
        for (int kt = 0; kt < 7; ++kt) {
            bf16x8 a0 = *(const bf16x8*)&cam_s[lo][kt*32 + hi*8];
            bf16x8 a1 = *(const bf16x8*)&cam_s[16 + lo][kt*32 + hi*8];
            bf16x8 bb = *(const bf16x8*)&feat_s[w*16 + lo][kt*32 + hi*8];
            acc[0] = __builtin_amdgcn_mfma_f32_16x16x32_bf16(a0, bb, acc[0], 0, 0, 0);
            acc[1] = __builtin_amdgcn_mfma_f32_16x16x32_bf16(a1, bb, acc[1], 0, 0, 0);
        }
#pragma unroll
        for (int mo = 0; mo < 2; ++mo)
#pragma unroll
            for (int reg = 0; reg < 4; ++reg) {
                int c = mo*16 + hi*4 + reg;
                int i = ic*64 + w*16 + lo;
                g_bf[((size_t)b*32 + c)*512 + i] = f2bf(acc[mo][reg]);
            }
    }
}

// ---------------- Kernel 3: Wvs[o][i] = sum_d Wv[o][d]*Ws[d][i] (bf16 out); wvbs[o] = Wv[o]·bs
__global__ __launch_bounds__(256) void k3_wvs(
    const float* __restrict__ Wv, const float* __restrict__ Ws, const float* __restrict__ bs,
    unsigned short* __restrict__ Wvs_bf, float* __restrict__ wvbs)
{
    __shared__ float red[256];
    const int o = blockIdx.x, t = threadIdx.x;
    float a0 = 0.f, a1 = 0.f;
    for (int d = 0; d < 512; ++d) {
        float wv = Wv[o*512 + d];
        a0 += wv * Ws[d*512 + t];
        a1 += wv * Ws[d*512 + t + 256];
    }
    Wvs_bf[o*512 + t]       = f2bf(a0);
    Wvs_bf[o*512 + t + 256] = f2bf(a1);
    red[t] = Wv[o*512 + t] * bs[t] + Wv[o*512 + t + 256] * bs[t + 256];
    __syncthreads();
    for (int s2 = 128; s2 > 0; s2 >>= 1) {
        if (t < s2) red[t] += red[t + s2];
        __syncthreads();
    }
    if (t == 0) wvbs[o] = red[0];
}

// ---------------- Kernel 4: tv[bc][o] = (g[bc]·Wvs[o] + cs*wvbs[o])/(cs+1e-10) + bv[o]
__global__ __launch_bounds__(64) void k4_tv(
    const unsigned short* __restrict__ g_bf, const unsigned short* __restrict__ Wvs_bf,
    const float* __restrict__ camsum, const float* __restrict__ wvbs,
    const float* __restrict__ bv, float* __restrict__ tv)
{
    const int m0 = blockIdx.x * 32;
    const int l = threadIdx.x, lo = l & 15, hi = l >> 4;
    f32x4 acc[2][8];
#pragma unroll
    for (int i = 0; i < 2; ++i)
#pragma unroll
        for (int j = 0; j < 8; ++j) acc[i][j] = (f32x4)(0.f);
    for (int k0 = 0; k0 < 512; k0 += 32) {
        bf16x8 a0 = *(const bf16x8*)&g_bf[(m0 + lo)*512 + k0 + hi*8];
        bf16x8 a1 = *(const bf16x8*)&g_bf[(m0 + 16 + lo)*512 + k0 + hi*8];
#pragma unroll
        for (int nf = 0; nf < 8; ++nf) {
            bf16x8 bb = *(const bf16x8*)&Wvs_bf[(nf*16 + lo)*512 + k0 + hi*8];
            acc[0][nf] = __builtin_amdgcn_mfma_f32_16x16x32_bf16(a0, bb, acc[0][nf], 0, 0, 0);
            acc[1][nf] = __builtin_amdgcn_mfma_f32_16x16x32_bf16(a1, bb, acc[1][nf], 0, 0, 0);
        }
    }
#pragma unroll
    for (int mo = 0; mo < 2; ++mo)
#pragma unroll
        for (int reg = 0; reg < 4; ++reg) {
            int bc = m0 + mo*16 + hi*4 + reg;
            float cs = camsum[bc];
            float inv = 1.f / (cs + 1e-10f);
#pragma unroll
            for (int nf = 0; nf < 8; ++nf) {
                int o = nf*16 + lo;
                tv[bc*128 + o] = (acc[mo][nf][reg] + cs * wvbs[o]) * inv + bv[o];
            }
        }
}

// ---------------- Kernel 5: ta[row][o] = fa[row]·Wa[o] + ba[o]  (fp32)
// grid 256 (4 rows each), block 128 (o)
__global__ __launch_bounds__(128) void k5_ta(
    const float* __restrict__ fa, const float* __restrict__ Wa,
    const float* __restrict__ ba, float* __restrict__ ta)
{
    __shared__ float fa_s[4 * 512];
    const int r0 = blockIdx.x * 4, t = threadIdx.x;
    for (int j = t; j < 512; j += 128)
        ((float4*)fa_s)[j] = ((const float4*)&fa[r0 * 512])[j];
    __syncthreads();
    float acc[4];
#pragma unroll
    for (int r = 0; r < 4; ++r) acc[r] = 0.f;
    const float4* wa4 = (const float4*)&Wa[t * 512];
    for (int j = 0; j < 128; ++j) {
        float4 wv = wa4[j];
#pragma unroll
        for (int r = 0; r < 4; ++r) {
            float4 fv = ((const float4*)&fa_s[r * 512])[j];
            acc[r] += wv.x*fv.x + wv.y*fv.y + wv.z*fv.z + wv.w*fv.w;
        }
    }
    float bao = ba[t];
#pragma unroll
    for (int r = 0; r < 4; ++r) ta[(r0 + r)*128 + t] = acc[r] + bao;
}

// ---------------- Kernel 6: losses. grid 1024 (s*32+c), block 256 (wave w: f=2w,2w+1).
__global__ __launch_bounds__(256) void k6_loss(
    const float* __restrict__ ta, const float* __restrict__ tv,
    const float* __restrict__ pred_a, const float* __restrict__ pred_v,
    const int* __restrict__ rand_frames, const int* __restrict__ rand_classes,
    float* __restrict__ out)
{
    const int blk = blockIdx.x;
    const int s = blk >> 5, c = blk & 31;
    const int t = threadIdx.x, w = t >> 6, l = t & 63;
    const float ta0 = ta[blk*128 + l], ta1 = ta[blk*128 + 64 + l];
    const float pa = pred_a[blk];
    const bool aa = pa > 0.3f;
    const int num = (int)(pa * 8.0f);
    const float LOGIT03 = -0.84729786f; // ln(0.3/0.7): sigmoid(x)>0.3 <=> x>LOGIT03
#pragma unroll
    for (int ff = 0; ff < 2; ++ff) {
        int f = w*2 + ff;
        // co: tv row (s,f,c)
        int row = (s*8 + f)*32 + c;
        float d0 = ta0 - tv[row*128 + l];
        float d1 = ta1 - tv[row*128 + 64 + l];
        float ss = d0*d0 + d1*d1;
        for (int m = 32; m > 0; m >>= 1) ss += __shfl_xor(ss, m);
        bool av = pred_v[(s*8 + f)*32 + c] > LOGIT03;
        if (l == 0) out[blk*8 + f] = (aa && av) ? ss * (1.f/128.f) : 0.f;
        // di: tv row (s^1, rand_frames, rand_classes)
        int fi = rand_frames[blk*8 + f];
        int ci = rand_classes[blk*8 + f];
        int row2 = ((s ^ 1)*8 + fi)*32 + ci;
        float e0 = ta0 - tv[row2*128 + l];
        float e1 = ta1 - tv[row2*128 + 64 + l];
        float s2 = e0*e0 + e1*e1;
        for (int m = 32; m > 0; m >>= 1) s2 += __shfl_xor(s2, m);
        if (l == 0) out[8192 + blk*8 + f] = (aa && (f < num)) ? s2 * (1.f/128.f) : 0.f;
    }
}

extern "C" void kernel_launch(void* const* d_in, const int* in_sizes, int n_in,
                              void* d_out, int out_size, void* d_ws, size_t ws_size,
                              hipStream_t stream) {
    const float* feat_a = (const float*)d_in[0];
    const float* pred_a = (const float*)d_in[1];
    const float* feat_v = (const float*)d_in[2];
    const float* pred_v = (const float*)d_in[3];
    const float* cam    = (const float*)d_in[4];
    const int* rand_frames  = (const int*)d_in[5];
    const int* rand_classes = (const int*)d_in[6];
    const float* Wt = (const float*)d_in[7];
    const float* bt = (const float*)d_in[8];
    const float* Ws = (const float*)d_in[9];
    const float* bs = (const float*)d_in[10];
    const float* Wa = (const float*)d_in[11];
    const float* ba = (const float*)d_in[12];
    const float* Wv = (const float*)d_in[13];
    const float* bv = (const float*)d_in[14];
    float* out = (float*)d_out;

    char* ws = (char*)d_ws;
    float* fa              = (float*)(ws + 0);                 // 1024*512*4   = 2 MB
    float* ta              = (float*)(ws + 2097152);           // 1024*128*4   = 512 KB
    // Wt_bf aliases ta: Wt_bf written by k0, read by k1; ta written by k5 (after k1)
    unsigned short* Wt_bf  = (unsigned short*)(ws + 2097152);  // 512*512*2    = 512 KB
    unsigned short* g_bf   = (unsigned short*)(ws + 2621440);  // 8192*512*2   = 8 MB
    float* camsum          = (float*)(ws + 11010048);          // 8192*4       = 32 KB
    unsigned short* Wvs_bf = (unsigned short*)(ws + 11042816); // 128*512*2    = 128 KB
    float* wvbs            = (float*)(ws + 11173888);          // 128*4
    float* tv              = (float*)(ws + 11174400);          // 8192*128*4   = 4 MB

    k0_wtbf<<<256, 256, 0, stream>>>(Wt, Wt_bf);
    k3_wvs<<<128, 256, 0, stream>>>(Wv, Ws, bs, Wvs_bf, wvbs);
    k1_fa<<<1024, 256, 0, stream>>>(feat_a, Wt_bf, bt, fa);
    k2_g<<<dim3(2, 256), 256, 0, stream>>>(feat_v, cam, g_bf, camsum);
    k4_tv<<<256, 64, 0, stream>>>(g_bf, Wvs_bf, camsum, wvbs, bv, tv);
    k5_ta<<<256, 128, 0, stream>>>(fa, Wa, ba, ta);
    k6_loss<<<1024, 256, 0, stream>>>(ta, tv, pred_a, pred_v, rand_frames, rand_classes, out);
}

// Round 3
// 422.814 us; speedup vs baseline: 1.2374x; 1.0901x over previous
//
#include <hip/hip_runtime.h>

// Problem constants: S=32, FRAME=8, CLS=32, D=512, HWA=8x8=64, HWV=14x14=196, DOUT=128

typedef __attribute__((ext_vector_type(8))) short bf16x8;
typedef __attribute__((ext_vector_type(4))) float f32x4;

__device__ __forceinline__ unsigned short f2bf(float x) {
    union { float f; unsigned u; } v; v.f = x;
    unsigned r = v.u + 0x7FFFu + ((v.u >> 16) & 1u);
    return (unsigned short)(r >> 16);
}
__device__ __forceinline__ unsigned pk2(float a, float b) {
    return (unsigned)f2bf(a) | ((unsigned)f2bf(b) << 16);
}

// ---------------- Kernel 0: Wt -> fragment-ordered bf16 WtF.
// WtF[((ot*16 + ks)*64 + l)*8 + j] = Wt[ot*16 + (l&15)][ks*32 + (l>>4)*8 + j]
// so k1's A-fragment load for (ot, ks) is one contiguous 1KB wave read.
__global__ __launch_bounds__(256) void k0_wtf(
    const float* __restrict__ Wt, unsigned short* __restrict__ WtF)
{
    int g = blockIdx.x * 256 + threadIdx.x;   // 0..32767 = 32 ot * 16 ks * 64 l
    int ot = g >> 10, ks = (g >> 6) & 15, l = g & 63;
    int lo = l & 15, hi = l >> 4;
    const float* src = &Wt[(ot*16 + lo) * 512 + ks*32 + hi*8];
    float4 f0 = ((const float4*)src)[0], f1 = ((const float4*)src)[1];
    uint4 u = { pk2(f0.x,f0.y), pk2(f0.z,f0.w), pk2(f1.x,f1.y), pk2(f1.z,f1.w) };
    *(uint4*)&WtF[(size_t)g * 8] = u;
}

// ---------------- Kernel 1: fa[b][o] = max_hw( sum_i Wt[o][i]*feat_a[b][i][hw] ) + bt[o]
// One block per b, 512 thr (8 waves). feat_a[b] staged once -> LDS [hw][k] bf16 64KB
// (16B-chunk XOR swizzle). Wave w: o-range [w*64, w*64+64), acc 4x4 frags (64 VGPR).
// A-frags from fragment-ordered WtF (contiguous 1KB coalesced, L2-hot).
__global__ __launch_bounds__(512, 4) void k1_fa(
    const float* __restrict__ feat_a, const unsigned short* __restrict__ WtF,
    const float* __restrict__ bt, float* __restrict__ fa)
{
    __shared__ unsigned short lds_b[64 * 512]; // [hw][k], 65536 B, swizzled 16B chunks
    const int b = blockIdx.x, t = threadIdx.x;
    const int w = t >> 6, l = t & 63, lo = l & 15, hi = l >> 4;

    // ---- stage: lane = hw, wave w handles koct = it*8 + w (8 kocts/wave)
    const float* fb = feat_a + (size_t)b * 32768;
    const int hw = l;
#pragma unroll 2
    for (int it = 0; it < 8; ++it) {
        int koct = it * 8 + w; // 0..63
        float v[8];
#pragma unroll
        for (int j = 0; j < 8; ++j)
            v[j] = fb[(koct * 8 + j) * 64 + hw]; // wave-wide coalesced 256B row read
        unsigned u[4];
#pragma unroll
        for (int j = 0; j < 4; ++j) u[j] = pk2(v[2*j], v[2*j + 1]);
        int chunk = koct ^ (hw & 7);
        *(uint4*)((char*)lds_b + hw * 1024 + chunk * 16) = *(uint4*)u;
    }
    __syncthreads();

    // ---- compute: 16 ks steps, no barriers
    f32x4 acc[4][4];
#pragma unroll
    for (int i = 0; i < 4; ++i)
#pragma unroll
        for (int j = 0; j < 4; ++j) acc[i][j] = (f32x4)(0.f);
    const unsigned short* wtf = WtF + (size_t)(w * 4) * 8192; // ot base = w*4; 16*64*8=8192
    for (int ks = 0; ks < 16; ++ks) {
        bf16x8 bfr[4];
#pragma unroll
        for (int nf = 0; nf < 4; ++nf) {
            int chunk = (ks * 4 + hi) ^ (lo & 7);
            bfr[nf] = *(const bf16x8*)((char*)lds_b + (nf*16 + lo) * 1024 + chunk * 16);
        }
#pragma unroll
        for (int mo = 0; mo < 4; ++mo) {
            bf16x8 afr = *(const bf16x8*)&wtf[(size_t)((mo*16 + ks)*64 + l) * 8];
#pragma unroll
            for (int nf = 0; nf < 4; ++nf)
                acc[mo][nf] = __builtin_amdgcn_mfma_f32_16x16x32_bf16(afr, bfr[nf], acc[mo][nf], 0, 0, 0);
        }
    }
    // ---- epilogue: D row=(l>>4)*4+reg (o), col=l&15 (hw). max over nf then 16 lanes.
    const int o0 = w * 64;
#pragma unroll
    for (int mo = 0; mo < 4; ++mo)
#pragma unroll
        for (int reg = 0; reg < 4; ++reg) {
            float m = fmaxf(fmaxf(acc[mo][0][reg], acc[mo][1][reg]),
                            fmaxf(acc[mo][2][reg], acc[mo][3][reg]));
            m = fmaxf(m, __shfl_xor(m, 1));
            m = fmaxf(m, __shfl_xor(m, 2));
            m = fmaxf(m, __shfl_xor(m, 4));
            m = fmaxf(m, __shfl_xor(m, 8));
            if (lo == 0) {
                int orow = o0 + mo*16 + hi*4 + reg;
                fa[(size_t)b * 512 + orow] = m + bt[orow];
            }
        }
}

// ---------------- Kernel 2: g[b][c][i] = sum_hw feat_v[b][i][hw]*cam[b][c][hw]; camsum
// grid (2 half, 256 b), 512 thr (8 waves). Double-buffered feat staging; wave w
// owns sub-tile (mo=w>>2, nf=w&3) of the 32c x 64i chunk output.
__global__ __launch_bounds__(512) void k2_g(
    const float* __restrict__ feat_v, const float* __restrict__ cam,
    unsigned short* __restrict__ g_bf, float* __restrict__ camsum)
{
    __shared__ unsigned short cam_s[32][232];     // [c][hw pad]
    __shared__ unsigned short feat_s[2][64][232]; // dbuf [i-chunk][hw pad]
    const int half = blockIdx.x, b = blockIdx.y, t = threadIdx.x;
    const int w = t >> 6, l = t & 63, lo = l & 15, hi = l >> 4;
    const int mo = w >> 2, nf = w & 3;

    const float* camb = &cam[b * 6272];
    for (int i4 = t; i4 < 1568; i4 += 512) { // 32*196/4
        int c = i4 / 49, h4 = (i4 - c*49) * 4;
        float4 v = ((const float4*)camb)[i4];
        *(unsigned*)&cam_s[c][h4]     = pk2(v.x, v.y);
        *(unsigned*)&cam_s[c][h4 + 2] = pk2(v.z, v.w);
    }
    for (int idx = t; idx < 32*28; idx += 512) { // cam pad k=196..223
        int c = idx / 28; cam_s[c][196 + (idx - c*28)] = 0;
    }
    for (int idx = t; idx < 2*64*28; idx += 512) { // feat pad, both buffers, once
        int bu = idx / 1792, r = (idx - bu*1792) / 28, hh = 196 + (idx % 28);
        feat_s[bu][r][hh] = 0;
    }
    if (half == 0) { // camsum fp32: c = t>>4, seg = lo (16 segs x 13)
        int c = t >> 4, seg = l & 15;
        int h0 = seg * 13, h1 = min(196, h0 + 13);
        float s = 0.f;
        const float* p = &camb[c * 196];
        for (int q = h0; q < h1; ++q) s += p[q];
        s += __shfl_xor(s, 1); s += __shfl_xor(s, 2);
        s += __shfl_xor(s, 4); s += __shfl_xor(s, 8);
        if (seg == 0) camsum[b*32 + c] = s;
    }

    // stage chunk helper
    auto STAGE = [&](int ic, int bu) {
        const float* fbv = &feat_v[((size_t)b*512 + ic*64) * 196];
        for (int i4 = t; i4 < 3136; i4 += 512) { // 64*196/4
            int r = i4 / 49, h4 = (i4 - r*49) * 4;
            float4 v = ((const float4*)fbv)[i4];
            *(unsigned*)&feat_s[bu][r][h4]     = pk2(v.x, v.y);
            *(unsigned*)&feat_s[bu][r][h4 + 2] = pk2(v.z, v.w);
        }
    };
    STAGE(half*4, 0);
    __syncthreads();
    for (int q = 0; q < 4; ++q) {
        int ic = half*4 + q;
        if (q < 3) STAGE(ic + 1, (q + 1) & 1); // loads overlap MFMA below
        f32x4 acc = (f32x4)(0.f);
#pragma unroll
        for (int kt = 0; kt < 7; ++kt) {
            bf16x8 a  = *(const bf16x8*)&cam_s[mo*16 + lo][kt*32 + hi*8];
            bf16x8 bb = *(const bf16x8*)&feat_s[q & 1][nf*16 + lo][kt*32 + hi*8];
            acc = __builtin_amdgcn_mfma_f32_16x16x32_bf16(a, bb, acc, 0, 0, 0);
        }
#pragma unroll
        for (int reg = 0; reg < 4; ++reg) {
            int c = mo*16 + hi*4 + reg;
            int i = ic*64 + nf*16 + lo;
            g_bf[((size_t)b*32 + c)*512 + i] = f2bf(acc[reg]);
        }
        __syncthreads();
    }
}

// ---------------- Kernel 3: Wvs = Wv @ Ws -> fragment-ordered bf16 WvsF; wvbs = Wv·bs
// grid 256 (o x i-half), block 256.
__global__ __launch_bounds__(256) void k3_wvs(
    const float* __restrict__ Wv, const float* __restrict__ Ws, const float* __restrict__ bs,
    unsigned short* __restrict__ WvsF, float* __restrict__ wvbs)
{
    __shared__ float red[256];
    const int o = blockIdx.x >> 1, ih = blockIdx.x & 1, t = threadIdx.x;
    const int i = ih*256 + t;
    float a0 = 0.f;
#pragma unroll 4
    for (int d = 0; d < 512; ++d)
        a0 += Wv[o*512 + d] * Ws[d*512 + i];
    // scatter into B-fragment order: WvsF[((nf*16+ks)*64 + hi*16+lo)*8 + j]
    int nf = o >> 4, lo2 = o & 15, ks = i >> 5, hi2 = (i >> 3) & 3, j = i & 7;
    WvsF[(size_t)(((nf*16 + ks)*64) + hi2*16 + lo2)*8 + j] = f2bf(a0);
    if (ih == 0) {
        red[t] = Wv[o*512 + t]*bs[t] + Wv[o*512 + t + 256]*bs[t + 256];
        __syncthreads();
        for (int s2 = 128; s2 > 0; s2 >>= 1) {
            if (t < s2) red[t] += red[t + s2];
            __syncthreads();
        }
        if (t == 0) wvbs[o] = red[0];
    }
}

// ---------------- Kernel 4: tv[bc][o] = (g[bc]·Wvs[o] + cs*wvbs[o])/(cs+1e-10) + bv[o]
// grid 256 (m-tile of 32 rows), block 256: wave w owns o-cols [w*32, w*32+32).
__global__ __launch_bounds__(256) void k4_tv(
    const unsigned short* __restrict__ g_bf, const unsigned short* __restrict__ WvsF,
    const float* __restrict__ camsum, const float* __restrict__ wvbs,
    const float* __restrict__ bv, float* __restrict__ tv)
{
    const int m0 = blockIdx.x * 32;
    const int t = threadIdx.x, w = t >> 6, l = t & 63, lo = l & 15, hi = l >> 4;
    f32x4 acc[2][2];
#pragma unroll
    for (int i = 0; i < 2; ++i)
#pragma unroll
        for (int j = 0; j < 2; ++j) acc[i][j] = (f32x4)(0.f);
    for (int ks = 0; ks < 16; ++ks) {
        bf16x8 a0 = *(const bf16x8*)&g_bf[(size_t)(m0 + lo)*512 + ks*32 + hi*8];
        bf16x8 a1 = *(const bf16x8*)&g_bf[(size_t)(m0 + 16 + lo)*512 + ks*32 + hi*8];
#pragma unroll
        for (int nn = 0; nn < 2; ++nn) {
            int nf = w*2 + nn;
            bf16x8 bb = *(const bf16x8*)&WvsF[(size_t)((nf*16 + ks)*64 + l) * 8];
            acc[0][nn] = __builtin_amdgcn_mfma_f32_16x16x32_bf16(a0, bb, acc[0][nn], 0, 0, 0);
            acc[1][nn] = __builtin_amdgcn_mfma_f32_16x16x32_bf16(a1, bb, acc[1][nn], 0, 0, 0);
        }
    }
#pragma unroll
    for (int mo = 0; mo < 2; ++mo)
#pragma unroll
        for (int reg = 0; reg < 4; ++reg) {
            int bc = m0 + mo*16 + hi*4 + reg;
            float cs = camsum[bc];
            float inv = 1.f / (cs + 1e-10f);
#pragma unroll
            for (int nn = 0; nn < 2; ++nn) {
                int o = (w*2 + nn)*16 + lo;
                tv[(size_t)bc*128 + o] = (acc[mo][nn][reg] + cs * wvbs[o]) * inv + bv[o];
            }
        }
}

// ---------------- Kernel 5: ta[row][o] = fa[row]·Wa[o] + ba[o]  (fp32)
__global__ __launch_bounds__(128) void k5_ta(
    const float* __restrict__ fa, const float* __restrict__ Wa,
    const float* __restrict__ ba, float* __restrict__ ta)
{
    __shared__ float fa_s[4 * 512];
    const int r0 = blockIdx.x * 4, t = threadIdx.x;
    for (int j = t; j < 512; j += 128)
        ((float4*)fa_s)[j] = ((const float4*)&fa[r0 * 512])[j];
    __syncthreads();
    float acc[4];
#pragma unroll
    for (int r = 0; r < 4; ++r) acc[r] = 0.f;
    const float4* wa4 = (const float4*)&Wa[t * 512];
#pragma unroll 4
    for (int j = 0; j < 128; ++j) {
        float4 wv = wa4[j];
#pragma unroll
        for (int r = 0; r < 4; ++r) {
            float4 fv = ((const float4*)&fa_s[r * 512])[j];
            acc[r] += wv.x*fv.x + wv.y*fv.y + wv.z*fv.z + wv.w*fv.w;
        }
    }
    float bao = ba[t];
#pragma unroll
    for (int r = 0; r < 4; ++r) ta[(r0 + r)*128 + t] = acc[r] + bao;
}

// ---------------- Kernel 6: losses. grid 1024 (s*32+c), block 256 (wave w: f=2w,2w+1).
__global__ __launch_bounds__(256) void k6_loss(
    const float* __restrict__ ta, const float* __restrict__ tv,
    const float* __restrict__ pred_a, const float* __restrict__ pred_v,
    const int* __restrict__ rand_frames, const int* __restrict__ rand_classes,
    float* __restrict__ out)
{
    const int blk = blockIdx.x;
    const int s = blk >> 5, c = blk & 31;
    const int t = threadIdx.x, w = t >> 6, l = t & 63;
    const float ta0 = ta[blk*128 + l], ta1 = ta[blk*128 + 64 + l];
    const float pa = pred_a[blk];
    const bool aa = pa > 0.3f;
    const int num = (int)(pa * 8.0f);
    const float LOGIT03 = -0.84729786f; // ln(0.3/0.7)
#pragma unroll
    for (int ff = 0; ff < 2; ++ff) {
        int f = w*2 + ff;
        int row = (s*8 + f)*32 + c;
        float d0 = ta0 - tv[row*128 + l];
        float d1 = ta1 - tv[row*128 + 64 + l];
        float ss = d0*d0 + d1*d1;
        for (int m = 32; m > 0; m >>= 1) ss += __shfl_xor(ss, m);
        bool av = pred_v[(s*8 + f)*32 + c] > LOGIT03;
        if (l == 0) out[blk*8 + f] = (aa && av) ? ss * (1.f/128.f) : 0.f;
        int fi = rand_frames[blk*8 + f];
        int ci = rand_classes[blk*8 + f];
        int row2 = ((s ^ 1)*8 + fi)*32 + ci;
        float e0 = ta0 - tv[row2*128 + l];
        float e1 = ta1 - tv[row2*128 + 64 + l];
        float s2 = e0*e0 + e1*e1;
        for (int m = 32; m > 0; m >>= 1) s2 += __shfl_xor(s2, m);
        if (l == 0) out[8192 + blk*8 + f] = (aa && (f < num)) ? s2 * (1.f/128.f) : 0.f;
    }
}

extern "C" void kernel_launch(void* const* d_in, const int* in_sizes, int n_in,
                              void* d_out, int out_size, void* d_ws, size_t ws_size,
                              hipStream_t stream) {
    const float* feat_a = (const float*)d_in[0];
    const float* pred_a = (const float*)d_in[1];
    const float* feat_v = (const float*)d_in[2];
    const float* pred_v = (const float*)d_in[3];
    const float* cam    = (const float*)d_in[4];
    const int* rand_frames  = (const int*)d_in[5];
    const int* rand_classes = (const int*)d_in[6];
    const float* Wt = (const float*)d_in[7];
    const float* bt = (const float*)d_in[8];
    const float* Ws = (const float*)d_in[9];
    const float* bs = (const float*)d_in[10];
    const float* Wa = (const float*)d_in[11];
    const float* ba = (const float*)d_in[12];
    const float* Wv = (const float*)d_in[13];
    const float* bv = (const float*)d_in[14];
    float* out = (float*)d_out;

    char* ws = (char*)d_ws;
    float* fa              = (float*)(ws + 0);                 // 2 MB
    float* ta              = (float*)(ws + 2097152);           // 512 KB
    // WtF aliases ta: written k0, read k1; ta written by k5 (after k1)
    unsigned short* WtF    = (unsigned short*)(ws + 2097152);  // 512 KB
    unsigned short* g_bf   = (unsigned short*)(ws + 2621440);  // 8 MB
    float* camsum          = (float*)(ws + 11010048);          // 32 KB
    unsigned short* WvsF   = (unsigned short*)(ws + 11042816); // 128 KB
    float* wvbs            = (float*)(ws + 11173888);          // 512 B
    float* tv              = (float*)(ws + 11174400);          // 4 MB

    k0_wtf<<<128, 256, 0, stream>>>(Wt, WtF);
    k3_wvs<<<256, 256, 0, stream>>>(Wv, Ws, bs, WvsF, wvbs);
    k1_fa<<<1024, 512, 0, stream>>>(feat_a, WtF, bt, fa);
    k2_g<<<dim3(2, 256), 512, 0, stream>>>(feat_v, cam, g_bf, camsum);
    k4_tv<<<256, 256, 0, stream>>>(g_bf, WvsF, camsum, wvbs, bv, tv);
    k5_ta<<<256, 128, 0, stream>>>(fa, Wa, ba, ta);
    k6_loss<<<1024, 256, 0, stream>>>(ta, tv, pred_a, pred_v, rand_frames, rand_classes, out);
}

// Round 6
// 397.632 us; speedup vs baseline: 1.3158x; 1.0633x over previous
//
#include <hip/hip_runtime.h>

// Problem constants: S=32, FRAME=8, CLS=32, D=512, HWA=8x8=64, HWV=14x14=196, DOUT=128

typedef __attribute__((ext_vector_type(8))) short bf16x8;
typedef __attribute__((ext_vector_type(4))) float f32x4;

__device__ __forceinline__ unsigned short f2bf(float x) {
    union { float f; unsigned u; } v; v.f = x;
    unsigned r = v.u + 0x7FFFu + ((v.u >> 16) & 1u);
    return (unsigned short)(r >> 16);
}
__device__ __forceinline__ unsigned pk2(float a, float b) {
    return (unsigned)f2bf(a) | ((unsigned)f2bf(b) << 16);
}

// ---------------- Kernel 0: Wt -> fragment-ordered bf16 WtF.
// WtF[((ot*16 + ks)*64 + l)*8 + j] = Wt[ot*16 + (l&15)][ks*32 + (l>>4)*8 + j]
__global__ __launch_bounds__(256) void k0_wtf(
    const float* __restrict__ Wt, unsigned short* __restrict__ WtF)
{
    int g = blockIdx.x * 256 + threadIdx.x;   // 0..32767 = 32 ot * 16 ks * 64 l
    int ot = g >> 10, ks = (g >> 6) & 15, l = g & 63;
    int lo = l & 15, hi = l >> 4;
    const float* src = &Wt[(ot*16 + lo) * 512 + ks*32 + hi*8];
    float4 f0 = ((const float4*)src)[0], f1 = ((const float4*)src)[1];
    uint4 u = { pk2(f0.x,f0.y), pk2(f0.z,f0.w), pk2(f1.x,f1.y), pk2(f1.z,f1.w) };
    *(uint4*)&WtF[(size_t)g * 8] = u;
}

// ---------------- Kernel 1: fa[b][o] = max_hw( sum_i Wt[o][i]*feat_a[b][i][hw] ) + bt[o]
// One block per b, 512 thr (8 waves). Staging: each thread loads a [4k][4hw]
// micro-tile via 4x float4 (coalesced), in-register transpose, 4x ds_write_b64
// into swizzled [hw][k] bf16 LDS (64KB). ks-loop software-pipelines A-frag loads.
__global__ __launch_bounds__(512, 4) void k1_fa(
    const float* __restrict__ feat_a, const unsigned short* __restrict__ WtF,
    const float* __restrict__ bt, float* __restrict__ fa)
{
    __shared__ unsigned short lds_b[64 * 512]; // [hw][k], 65536 B, swizzled 16B chunks
    const int b = blockIdx.x, t = threadIdx.x;
    const int w = t >> 6, l = t & 63, lo = l & 15, hi = l >> 4;

    const unsigned short* wtf = WtF + (size_t)(w * 4) * 8192; // ot base = w*4

    // prologue A-frag load (ks=0) overlaps staging
    bf16x8 afrA[4], afrB[4];
#pragma unroll
    for (int mo = 0; mo < 4; ++mo)
        afrA[mo] = *(const bf16x8*)&wtf[(size_t)((mo*16 + 0)*64 + l) * 8];

    // ---- stage: 4 iters x 512 thr = 2048 micro-tiles of [4k][4hw]
    const float4* fb4 = (const float4*)(feat_a + (size_t)b * 32768);
#pragma unroll
    for (int it = 0; it < 4; ++it) {
        int tp = it * 512 + t;          // 0..2047
        int hq = tp & 15, kq = tp >> 4; // hw-quad, k-quad
        int hw0 = hq * 4, k0 = kq * 4;
        float4 v0 = fb4[(k0 + 0) * 16 + hq];
        float4 v1 = fb4[(k0 + 1) * 16 + hq];
        float4 v2 = fb4[(k0 + 2) * 16 + hq];
        float4 v3 = fb4[(k0 + 3) * 16 + hq];
        int koct = kq >> 1, bo = (kq & 1) * 8;
        float a0[4] = {v0.x, v0.y, v0.z, v0.w};
        float a1[4] = {v1.x, v1.y, v1.z, v1.w};
        float a2[4] = {v2.x, v2.y, v2.z, v2.w};
        float a3[4] = {v3.x, v3.y, v3.z, v3.w};
#pragma unroll
        for (int r = 0; r < 4; ++r) {
            int hw = hw0 + r;
            uint2 u = { pk2(a0[r], a1[r]), pk2(a2[r], a3[r]) };
            int chunk = koct ^ (hw & 7);
            *(uint2*)((char*)lds_b + hw * 1024 + chunk * 16 + bo) = u;
        }
    }
    __syncthreads();

    // ---- compute: 16 ks steps, 2-phase software pipeline on A-frags
    f32x4 acc[4][4];
#pragma unroll
    for (int i = 0; i < 4; ++i)
#pragma unroll
        for (int j = 0; j < 4; ++j) acc[i][j] = (f32x4)(0.f);

#pragma unroll
    for (int ks2 = 0; ks2 < 8; ++ks2) {
        { // phase A: ks = 2*ks2 (uses afrA), prefetch afrB for ks+1
            const int ks = 2 * ks2;
#pragma unroll
            for (int mo = 0; mo < 4; ++mo)
                afrB[mo] = *(const bf16x8*)&wtf[(size_t)((mo*16 + ks + 1)*64 + l) * 8];
            bf16x8 bfr[4];
#pragma unroll
            for (int nf = 0; nf < 4; ++nf) {
                int chunk = (ks * 4 + hi) ^ (lo & 7);
                bfr[nf] = *(const bf16x8*)((char*)lds_b + (nf*16 + lo) * 1024 + chunk * 16);
            }
#pragma unroll
            for (int mo = 0; mo < 4; ++mo)
#pragma unroll
                for (int nf = 0; nf < 4; ++nf)
                    acc[mo][nf] = __builtin_amdgcn_mfma_f32_16x16x32_bf16(afrA[mo], bfr[nf], acc[mo][nf], 0, 0, 0);
        }
        { // phase B: ks = 2*ks2+1 (uses afrB), prefetch afrA for ks+2
            const int ks = 2 * ks2 + 1;
            if (ks2 < 7) {
#pragma unroll
                for (int mo = 0; mo < 4; ++mo)
                    afrA[mo] = *(const bf16x8*)&wtf[(size_t)((mo*16 + ks + 1)*64 + l) * 8];
            }
            bf16x8 bfr[4];
#pragma unroll
            for (int nf = 0; nf < 4; ++nf) {
                int chunk = (ks * 4 + hi) ^ (lo & 7);
                bfr[nf] = *(const bf16x8*)((char*)lds_b + (nf*16 + lo) * 1024 + chunk * 16);
            }
#pragma unroll
            for (int mo = 0; mo < 4; ++mo)
#pragma unroll
                for (int nf = 0; nf < 4; ++nf)
                    acc[mo][nf] = __builtin_amdgcn_mfma_f32_16x16x32_bf16(afrB[mo], bfr[nf], acc[mo][nf], 0, 0, 0);
        }
    }

    // ---- epilogue: D row=(l>>4)*4+reg (o), col=l&15 (hw). max over nf then 16 lanes.
    const int o0 = w * 64;
#pragma unroll
    for (int mo = 0; mo < 4; ++mo)
#pragma unroll
        for (int reg = 0; reg < 4; ++reg) {
            float m = fmaxf(fmaxf(acc[mo][0][reg], acc[mo][1][reg]),
                            fmaxf(acc[mo][2][reg], acc[mo][3][reg]));
            m = fmaxf(m, __shfl_xor(m, 1));
            m = fmaxf(m, __shfl_xor(m, 2));
            m = fmaxf(m, __shfl_xor(m, 4));
            m = fmaxf(m, __shfl_xor(m, 8));
            if (lo == 0) {
                int orow = o0 + mo*16 + hi*4 + reg;
                fa[(size_t)b * 512 + orow] = m + bt[orow];
            }
        }
}

// ---------------- Kernel 2: g[b][c][i] = sum_hw feat_v[b][i][hw]*cam[b][c][hw]; camsum
// grid (2 half, 256 b), 512 thr (8 waves). Double-buffered feat staging.
__global__ __launch_bounds__(512) void k2_g(
    const float* __restrict__ feat_v, const float* __restrict__ cam,
    unsigned short* __restrict__ g_bf, float* __restrict__ camsum)
{
    __shared__ unsigned short cam_s[32][232];     // [c][hw pad]
    __shared__ unsigned short feat_s[2][64][232]; // dbuf [i-chunk][hw pad]
    const int half = blockIdx.x, b = blockIdx.y, t = threadIdx.x;
    const int w = t >> 6, l = t & 63, lo = l & 15, hi = l >> 4;
    const int mo = w >> 2, nf = w & 3;

    const float* camb = &cam[b * 6272];
    for (int i4 = t; i4 < 1568; i4 += 512) { // 32*196/4
        int c = i4 / 49, h4 = (i4 - c*49) * 4;
        float4 v = ((const float4*)camb)[i4];
        *(unsigned*)&cam_s[c][h4]     = pk2(v.x, v.y);
        *(unsigned*)&cam_s[c][h4 + 2] = pk2(v.z, v.w);
    }
    for (int idx = t; idx < 32*28; idx += 512) { // cam pad k=196..223
        int c = idx / 28; cam_s[c][196 + (idx - c*28)] = 0;
    }
    for (int idx = t; idx < 2*64*28; idx += 512) { // feat pad, both buffers, once
        int bu = idx / 1792, r = (idx - bu*1792) / 28, hh = 196 + (idx % 28);
        feat_s[bu][r][hh] = 0;
    }
    if (half == 0) { // camsum fp32: c = t>>4, seg = l&15 (16 segs x 13)
        int c = t >> 4, seg = l & 15;
        int h0 = seg * 13, h1 = min(196, h0 + 13);
        float s = 0.f;
        const float* p = &camb[c * 196];
        for (int q = h0; q < h1; ++q) s += p[q];
        s += __shfl_xor(s, 1); s += __shfl_xor(s, 2);
        s += __shfl_xor(s, 4); s += __shfl_xor(s, 8);
        if (seg == 0) camsum[b*32 + c] = s;
    }

    auto STAGE = [&](int ic, int bu) {
        const float* fbv = &feat_v[((size_t)b*512 + ic*64) * 196];
        for (int i4 = t; i4 < 3136; i4 += 512) { // 64*196/4
            int r = i4 / 49, h4 = (i4 - r*49) * 4;
            float4 v = ((const float4*)fbv)[i4];
            *(unsigned*)&feat_s[bu][r][h4]     = pk2(v.x, v.y);
            *(unsigned*)&feat_s[bu][r][h4 + 2] = pk2(v.z, v.w);
        }
    };
    STAGE(half*4, 0);
    __syncthreads();
    for (int q = 0; q < 4; ++q) {
        int ic = half*4 + q;
        if (q < 3) STAGE(ic + 1, (q + 1) & 1); // loads overlap MFMA below
        f32x4 acc = (f32x4)(0.f);
#pragma unroll
        for (int kt = 0; kt < 7; ++kt) {
            bf16x8 a  = *(const bf16x8*)&cam_s[mo*16 + lo][kt*32 + hi*8];
            bf16x8 bb = *(const bf16x8*)&feat_s[q & 1][nf*16 + lo][kt*32 + hi*8];
            acc = __builtin_amdgcn_mfma_f32_16x16x32_bf16(a, bb, acc, 0, 0, 0);
        }
#pragma unroll
        for (int reg = 0; reg < 4; ++reg) {
            int c = mo*16 + hi*4 + reg;
            int i = ic*64 + nf*16 + lo;
            g_bf[((size_t)b*32 + c)*512 + i] = f2bf(acc[reg]);
        }
        __syncthreads();
    }
}

// ---------------- Kernel 3: Wvs = Wv @ Ws -> fragment-ordered bf16 WvsF; wvbs = Wv·bs
__global__ __launch_bounds__(256) void k3_wvs(
    const float* __restrict__ Wv, const float* __restrict__ Ws, const float* __restrict__ bs,
    unsigned short* __restrict__ WvsF, float* __restrict__ wvbs)
{
    __shared__ float red[256];
    const int o = blockIdx.x >> 1, ih = blockIdx.x & 1, t = threadIdx.x;
    const int i = ih*256 + t;
    float a0 = 0.f;
#pragma unroll 8
    for (int d = 0; d < 512; ++d)
        a0 += Wv[o*512 + d] * Ws[d*512 + i];
    int nf = o >> 4, lo2 = o & 15, ks = i >> 5, hi2 = (i >> 3) & 3, j = i & 7;
    WvsF[(size_t)(((nf*16 + ks)*64) + hi2*16 + lo2)*8 + j] = f2bf(a0);
    if (ih == 0) {
        red[t] = Wv[o*512 + t]*bs[t] + Wv[o*512 + t + 256]*bs[t + 256];
        __syncthreads();
        for (int s2 = 128; s2 > 0; s2 >>= 1) {
            if (t < s2) red[t] += red[t + s2];
            __syncthreads();
        }
        if (t == 0) wvbs[o] = red[0];
    }
}

// ---------------- Kernel 4: tv[bc][o] = (g[bc]·Wvs[o] + cs*wvbs[o])/(cs+1e-10) + bv[o]
// grid 512 (m-tile of 16 rows), block 256: wave w owns o-cols [w*32, w*32+32).
__global__ __launch_bounds__(256) void k4_tv(
    const unsigned short* __restrict__ g_bf, const unsigned short* __restrict__ WvsF,
    const float* __restrict__ camsum, const float* __restrict__ wvbs,
    const float* __restrict__ bv, float* __restrict__ tv)
{
    const int m0 = blockIdx.x * 16;
    const int t = threadIdx.x, w = t >> 6, l = t & 63, lo = l & 15, hi = l >> 4;
    f32x4 acc[2];
    acc[0] = (f32x4)(0.f); acc[1] = (f32x4)(0.f);
    for (int ks = 0; ks < 16; ++ks) {
        bf16x8 a0 = *(const bf16x8*)&g_bf[(size_t)(m0 + lo)*512 + ks*32 + hi*8];
#pragma unroll
        for (int nn = 0; nn < 2; ++nn) {
            int nf = w*2 + nn;
            bf16x8 bb = *(const bf16x8*)&WvsF[(size_t)((nf*16 + ks)*64 + l) * 8];
            acc[nn] = __builtin_amdgcn_mfma_f32_16x16x32_bf16(a0, bb, acc[nn], 0, 0, 0);
        }
    }
#pragma unroll
    for (int reg = 0; reg < 4; ++reg) {
        int bc = m0 + hi*4 + reg;
        float cs = camsum[bc];
        float inv = 1.f / (cs + 1e-10f);
#pragma unroll
        for (int nn = 0; nn < 2; ++nn) {
            int o = (w*2 + nn)*16 + lo;
            tv[(size_t)bc*128 + o] = (acc[nn][reg] + cs * wvbs[o]) * inv + bv[o];
        }
    }
}

// ---------------- Kernel 5: ta[row][o] = fa[row]·Wa[o] + ba[o]  (fp32)
__global__ __launch_bounds__(128) void k5_ta(
    const float* __restrict__ fa, const float* __restrict__ Wa,
    const float* __restrict__ ba, float* __restrict__ ta)
{
    __shared__ float fa_s[4 * 512];
    const int r0 = blockIdx.x * 4, t = threadIdx.x;
    for (int j = t; j < 512; j += 128)
        ((float4*)fa_s)[j] = ((const float4*)&fa[r0 * 512])[j];
    __syncthreads();
    float acc[4];
#pragma unroll
    for (int r = 0; r < 4; ++r) acc[r] = 0.f;
    const float4* wa4 = (const float4*)&Wa[t * 512];
#pragma unroll 8
    for (int j = 0; j < 128; ++j) {
        float4 wv = wa4[j];
#pragma unroll
        for (int r = 0; r < 4; ++r) {
            float4 fv = ((const float4*)&fa_s[r * 512])[j];
            acc[r] += wv.x*fv.x + wv.y*fv.y + wv.z*fv.z + wv.w*fv.w;
        }
    }
    float bao = ba[t];
#pragma unroll
    for (int r = 0; r < 4; ++r) ta[(r0 + r)*128 + t] = acc[r] + bao;
}

// ---------------- Kernel 6: losses. grid 1024 (s*32+c), block 256 (wave w: f=2w,2w+1).
__global__ __launch_bounds__(256) void k6_loss(
    const float* __restrict__ ta, const float* __restrict__ tv,
    const float* __restrict__ pred_a, const float* __restrict__ pred_v,
    const int* __restrict__ rand_frames, const int* __restrict__ rand_classes,
    float* __restrict__ out)
{
    const int blk = blockIdx.x;
    const int s = blk >> 5, c = blk & 31;
    const int t = threadIdx.x, w = t >> 6, l = t & 63;
    const float ta0 = ta[blk*128 + l], ta1 = ta[blk*128 + 64 + l];
    const float pa = pred_a[blk];
    const bool aa = pa > 0.3f;
    const int num = (int)(pa * 8.0f);
    const float LOGIT03 = -0.84729786f; // ln(0.3/0.7)
#pragma unroll
    for (int ff = 0; ff < 2; ++ff) {
        int f = w*2 + ff;
        int row = (s*8 + f)*32 + c;
        float d0 = ta0 - tv[row*128 + l];
        float d1 = ta1 - tv[row*128 + 64 + l];
        float ss = d0*d0 + d1*d1;
        for (int m = 32; m > 0; m >>= 1) ss += __shfl_xor(ss, m);
        bool av = pred_v[(s*8 + f)*32 + c] > LOGIT03;
        if (l == 0) out[blk*8 + f] = (aa && av) ? ss * (1.f/128.f) : 0.f;
        int fi = rand_frames[blk*8 + f];
        int ci = rand_classes[blk*8 + f];
        int row2 = ((s ^ 1)*8 + fi)*32 + ci;
        float e0 = ta0 - tv[row2*128 + l];
        float e1 = ta1 - tv[row2*128 + 64 + l];
        float s2 = e0*e0 + e1*e1;
        for (int m = 32; m > 0; m >>= 1) s2 += __shfl_xor(s2, m);
        if (l == 0) out[8192 + blk*8 + f] = (aa && (f < num)) ? s2 * (1.f/128.f) : 0.f;
    }
}

extern "C" void kernel_launch(void* const* d_in, const int* in_sizes, int n_in,
                              void* d_out, int out_size, void* d_ws, size_t ws_size,
                              hipStream_t stream) {
    const float* feat_a = (const float*)d_in[0];
    const float* pred_a = (const float*)d_in[1];
    const float* feat_v = (const float*)d_in[2];
    const float* pred_v = (const float*)d_in[3];
    const float* cam    = (const float*)d_in[4];
    const int* rand_frames  = (const int*)d_in[5];
    const int* rand_classes = (const int*)d_in[6];
    const float* Wt = (const float*)d_in[7];
    const float* bt = (const float*)d_in[8];
    const float* Ws = (const float*)d_in[9];
    const float* bs = (const float*)d_in[10];
    const float* Wa = (const float*)d_in[11];
    const float* ba = (const float*)d_in[12];
    const float* Wv = (const float*)d_in[13];
    const float* bv = (const float*)d_in[14];
    float* out = (float*)d_out;

    char* ws = (char*)d_ws;
    float* fa              = (float*)(ws + 0);                 // 2 MB
    float* ta              = (float*)(ws + 2097152);           // 512 KB
    unsigned short* WtF    = (unsigned short*)(ws + 2097152);  // aliases ta (k0/k1 before k5)
    unsigned short* g_bf   = (unsigned short*)(ws + 2621440);  // 8 MB
    float* camsum          = (float*)(ws + 11010048);          // 32 KB
    unsigned short* WvsF   = (unsigned short*)(ws + 11042816); // 128 KB
    float* wvbs            = (float*)(ws + 11173888);          // 512 B
    float* tv              = (float*)(ws + 11174400);          // 4 MB

    k0_wtf<<<128, 256, 0, stream>>>(Wt, WtF);
    k3_wvs<<<256, 256, 0, stream>>>(Wv, Ws, bs, WvsF, wvbs);
    k1_fa<<<1024, 512, 0, stream>>>(feat_a, WtF, bt, fa);
    k2_g<<<dim3(2, 256), 512, 0, stream>>>(feat_v, cam, g_bf, camsum);
    k4_tv<<<512, 256, 0, stream>>>(g_bf, WvsF, camsum, wvbs, bv, tv);
    k5_ta<<<256, 128, 0, stream>>>(fa, Wa, ba, ta);
    k6_loss<<<1024, 256, 0, stream>>>(ta, tv, pred_a, pred_v, rand_frames, rand_classes, out);
}